// Round 1
// 277.007 us; speedup vs baseline: 1.0476x; 1.0476x over previous
//
#include <hip/hip_runtime.h>

#define N_NODES 50000
#define N_EDGES 800000
#define FEATS 128
#define NCHUNK 196            // ceil(50000/256)
#define CPAD 50176            // NCHUNK*256 (counts/loc padded, zeroed)
#define GEMM_BX 196
#define GEMM_BLOCKS 588       // 3 planes x 196
#define SCAT_BLOCKS 3125      // 3125*256 = 800000 exactly
#define NTILE 782             // ceil(50000/64)
#define NF_WAVES 8192
#define STAT_BLOCKS 256
#define HIST_BLOCKS 512

typedef __attribute__((ext_vector_type(8))) short bf16x8;
typedef __attribute__((ext_vector_type(4))) float f32x4;

__device__ __forceinline__ unsigned short f2bf(float f){
  unsigned u = __float_as_uint(f);
  u += 0x7FFF + ((u >> 16) & 1);           // RNE
  return (unsigned short)(u >> 16);
}
// bf16 pair unpack, 1 VALU op per float
__device__ __forceinline__ void unpack8(uint4 p, float* f){
  f[0]=__uint_as_float(p.x << 16); f[1]=__uint_as_float(p.x & 0xffff0000u);
  f[2]=__uint_as_float(p.y << 16); f[3]=__uint_as_float(p.y & 0xffff0000u);
  f[4]=__uint_as_float(p.z << 16); f[5]=__uint_as_float(p.z & 0xffff0000u);
  f[6]=__uint_as_float(p.w << 16); f[7]=__uint_as_float(p.w & 0xffff0000u);
}

// ---------------- dispatch 1: BN stats (float4, blocks 0..255) || dst hist + rank capture (256..767)
__global__ __launch_bounds__(256) void stats_hist_kernel(
    const float* __restrict__ ftq, const float* __restrict__ ftk,
    float* __restrict__ sums, const int* __restrict__ dstE,
    int* __restrict__ counts, int* __restrict__ csums,
    unsigned short* __restrict__ rankE){
  __shared__ float red[4*FEATS];
  __shared__ int lchunk[NCHUNK];
  int tid = threadIdx.x, bid = blockIdx.x;
  if (bid < STAT_BLOCKS){
    for (int i = tid; i < 4*FEATS; i += 256) red[i] = 0.f;
    __syncthreads();
    int sub = tid >> 5, c4 = tid & 31;           // 32 lanes cover one 128-f row
    const float* Xs = (sub < 4) ? ftq : ftk;
    int so = (sub < 4) ? 0 : 2*FEATS;
    float a0=0,a1=0,a2=0,a3=0,b0=0,b1=0,b2=0,b3=0;
    #pragma unroll 4
    for (int r = bid*4 + (sub&3); r < N_NODES; r += STAT_BLOCKS*4){
      float4 x = *(const float4*)(Xs + (size_t)r*FEATS + c4*4);
      a0+=x.x; b0+=x.x*x.x; a1+=x.y; b1+=x.y*x.y;
      a2+=x.z; b2+=x.z*x.z; a3+=x.w; b3+=x.w*x.w;
    }
    // lane l and l+32 within a wave share (matrix, c4), differ in row set
    a0 += __shfl_xor(a0,32); a1 += __shfl_xor(a1,32);
    a2 += __shfl_xor(a2,32); a3 += __shfl_xor(a3,32);
    b0 += __shfl_xor(b0,32); b1 += __shfl_xor(b1,32);
    b2 += __shfl_xor(b2,32); b3 += __shfl_xor(b3,32);
    if ((tid & 63) < 32){
      int c0 = c4*4;
      atomicAdd(&red[so + c0+0], a0); atomicAdd(&red[so + c0+1], a1);
      atomicAdd(&red[so + c0+2], a2); atomicAdd(&red[so + c0+3], a3);
      atomicAdd(&red[so + FEATS + c0+0], b0); atomicAdd(&red[so + FEATS + c0+1], b1);
      atomicAdd(&red[so + FEATS + c0+2], b2); atomicAdd(&red[so + FEATS + c0+3], b3);
    }
    __syncthreads();
    for (int i = tid; i < 4*FEATS; i += 256) atomicAdd(&sums[i], red[i]);
  } else {
    for (int i = tid; i < NCHUNK; i += 256) lchunk[i] = 0;
    __syncthreads();
    for (int t = (bid-STAT_BLOCKS)*256 + tid; t < N_EDGES; t += HIST_BLOCKS*256){
      int d = dstE[t];
      int p = atomicAdd(&counts[d], 1);          // arrival order == CSR rank
      rankE[t] = (unsigned short)p;              // max in-degree ~50 << 65536
      atomicAdd(&lchunk[d >> 8], 1);
    }
    __syncthreads();
    for (int i = tid; i < NCHUNK; i += 256)
      if (lchunk[i]) atomicAdd(&csums[i], lchunk[i]);
  }
}

// ---------------- dispatch 2: chunk-local scans (0..195) || csums scan (196) || BN-fold (197..292)
__global__ __launch_bounds__(256) void scan_fold_kernel(
    const int* __restrict__ counts, const int* __restrict__ csums,
    int* __restrict__ loc, int* __restrict__ bscan,
    const float* __restrict__ Wq, const float* __restrict__ bq,
    const float* __restrict__ Wk, const float* __restrict__ Wv,
    const float* __restrict__ gq, const float* __restrict__ bqn,
    const float* __restrict__ gk, const float* __restrict__ bkn,
    const float* __restrict__ sums,
    unsigned short* __restrict__ Wb, float* __restrict__ bias){
  __shared__ int s[256];
  int tid = threadIdx.x, bid = blockIdx.x;
  if (bid < NCHUNK){
    int i = bid*256 + tid;
    int v = counts[i];                          // padded region is zero
    s[tid] = v; __syncthreads();
    for (int d = 1; d < 256; d <<= 1){
      int tv = (tid >= d) ? s[tid-d] : 0; __syncthreads();
      s[tid] += tv; __syncthreads();
    }
    loc[i] = s[tid] - v;                        // chunk-local exclusive
  } else if (bid == NCHUNK){
    int v = (tid < NCHUNK) ? csums[tid] : 0;
    s[tid] = v; __syncthreads();
    for (int d = 1; d < 256; d <<= 1){
      int tv = (tid >= d) ? s[tid-d] : 0; __syncthreads();
      s[tid] += tv; __syncthreads();
    }
    if (tid < NCHUNK) bscan[tid] = s[tid] - v;  // exclusive chunk bases
  } else {
    int wv = (bid - NCHUNK - 1)*4 + (tid >> 6); // 0..383
    int lane = tid & 63;
    int m = wv >> 7;                            // 0=q,1=v,2=k
    int o = wv & 127;
    const float* Wsrc = (m==0) ? Wq : (m==1) ? Wv : Wk;
    const float* g   = (m==2) ? gk : gq;
    const float* bb  = (m==2) ? bkn : bqn;
    const float* s0  = (m==2) ? (sums + 2*FEATS) : sums;
    const float invN = 1.0f / (float)N_NODES;
    float acc = 0.f;
    unsigned short w2[2];
    int i0 = lane*2;
    #pragma unroll
    for (int t = 0; t < 2; t++){
      int i = i0 + t;
      float mean = s0[i]*invN;
      float var  = s0[FEATS+i]*invN - mean*mean;
      float rstd = rsqrtf(var + 1e-5f);
      float scale = g[i]*rstd;
      float shift = bb[i] - mean*scale;
      float w = Wsrc[o*FEATS + i];
      w2[t] = f2bf(w*scale);
      acc += shift*w;
    }
    ((unsigned*)Wb)[(m*FEATS*FEATS + o*FEATS + i0) >> 1] =
        (unsigned)w2[0] | ((unsigned)w2[1] << 16);
    #pragma unroll
    for (int off = 1; off < 64; off <<= 1) acc += __shfl_xor(acc, off);
    if (lane == 0) bias[m*FEATS + o] = acc + ((m==0) ? bq[o] : 0.f);
  }
}

// ---------------- dispatch 3: persistent-B GEMM w/ A prefetch (0..587) || atomic-free CSR scatter (588..3712)
__global__ __launch_bounds__(256) void gemm_scatter_kernel(
    const float* __restrict__ ftq, const float* __restrict__ ftk,
    const unsigned short* __restrict__ Wball, const float* __restrict__ biasall,
    unsigned short* __restrict__ qv, unsigned short* __restrict__ kb,
    const int* __restrict__ dstE, const int* __restrict__ srcE,
    const int* __restrict__ loc, const int* __restrict__ bscan,
    const unsigned short* __restrict__ rankE, int* __restrict__ src_csr){
  __shared__ unsigned short Bs[FEATS][136];
  int tid = threadIdx.x, bid = blockIdx.x;
  if (bid >= GEMM_BLOCKS){
    int t = (bid - GEMM_BLOCKS)*256 + tid;     // exactly covers N_EDGES
    int d = dstE[t];
    src_csr[loc[d] + bscan[d >> 8] + (int)rankE[t]] = srcE[t];  // no atomics
    return;
  }
  int m = bid / GEMM_BX;                        // 0=q,1=v,2=k
  int bx = bid - m*GEMM_BX;
  const float* X = (m==2) ? ftk : ftq;
  { // stage this plane's B ONCE (dwordx4; stride-17-chunk rows -> 2-way = free)
    const uint4* srcp = (const uint4*)(Wball + m*FEATS*FEATS);
    for (int idx = tid; idx < FEATS*FEATS/8; idx += 256){
      int n = idx >> 4;
      int kk = (idx & 15) * 8;
      *(uint4*)&Bs[n][kk] = srcp[idx];
    }
  }
  __syncthreads();                              // only barrier in the kernel
  int wave = tid >> 6, lane = tid & 63;
  int mrow = lane & 15, quad = lane >> 4;
  unsigned short* Out = (m==2) ? kb : (qv + m*128);
  const int ostride = (m==2) ? FEATS : 256;
  float bv[8];
  #pragma unroll
  for (int ct = 0; ct < 8; ct++) bv[ct] = biasall[m*FEATS + ct*16 + mrow];
  float4 cur[8], nxt[8];
  auto loadx = [&](float4* buf, int t){
    int arow = t*64 + wave*16 + mrow;
    bool rok = arow < N_NODES;
    const float* xp = X + (size_t)(rok ? arow : 0)*FEATS + quad*8;
    #pragma unroll
    for (int kt = 0; kt < 4; kt++){
      float4 x0 = *(const float4*)(xp + kt*32);
      float4 x1 = *(const float4*)(xp + kt*32 + 4);
      if (!rok){ x0 = make_float4(0.f,0.f,0.f,0.f); x1 = x0; }
      buf[2*kt] = x0; buf[2*kt+1] = x1;
    }
  };
  loadx(cur, bx);
  for (int t = bx; t < NTILE; t += GEMM_BX){
    int tn = t + GEMM_BX;
    if (tn < NTILE) loadx(nxt, tn);             // prefetch next A tile under MFMA
    f32x4 acc[8];
    #pragma unroll
    for (int i = 0; i < 8; i++) acc[i] = (f32x4){0.f,0.f,0.f,0.f};
    #pragma unroll
    for (int kt = 0; kt < 4; kt++){
      float4 x0 = cur[2*kt], x1 = cur[2*kt+1];
      bf16x8 a;
      a[0]=(short)f2bf(x0.x); a[1]=(short)f2bf(x0.y); a[2]=(short)f2bf(x0.z); a[3]=(short)f2bf(x0.w);
      a[4]=(short)f2bf(x1.x); a[5]=(short)f2bf(x1.y); a[6]=(short)f2bf(x1.z); a[7]=(short)f2bf(x1.w);
      int kbk = kt*32 + quad*8;
      #pragma unroll
      for (int ct = 0; ct < 8; ct++){
        bf16x8 b = *(bf16x8*)&Bs[ct*16 + mrow][kbk];
        acc[ct] = __builtin_amdgcn_mfma_f32_16x16x32_bf16(a, b, acc[ct], 0, 0, 0);
      }
    }
    int row0 = t*64;
    #pragma unroll
    for (int ct = 0; ct < 8; ct++){
      int col = ct*16 + mrow;
      #pragma unroll
      for (int v = 0; v < 4; v++){
        int orow = row0 + wave*16 + quad*4 + v;
        unsigned ub = f2bf(acc[ct][v] + bv[ct]);
        unsigned partner = (unsigned)__shfl_xor((int)ub, 1);
        if (!(mrow & 1) && orow < N_NODES)
          *(unsigned*)&Out[(size_t)orow*ostride + col] = ub | (partner << 16);
      }
    }
    #pragma unroll
    for (int i = 0; i < 8; i++) cur[i] = nxt[i];
  }
}

// ---------------- dispatch 4: per-dst-node scores + max-free softmax agg, software-pipelined gather
__global__ __launch_bounds__(256) void node_fused_kernel(
    const unsigned short* __restrict__ qv, const unsigned short* __restrict__ kb,
    const float* __restrict__ attn, const int* __restrict__ src_csr,
    const int* __restrict__ loc, const int* __restrict__ bscan,
    float* __restrict__ out){
  int tid = threadIdx.x;
  int lane = tid & 63;
  int h = lane & 7, g = lane >> 3;
  int w = blockIdx.x*4 + (tid >> 6);
  const float L2E = 1.44269504f;
  float ar[16];
  {
    const uint4* ap = (const uint4*)(attn + h*16);
    uint4 a0 = ap[0], a1 = ap[1], a2 = ap[2], a3 = ap[3];
    ar[0]=__uint_as_float(a0.x); ar[1]=__uint_as_float(a0.y); ar[2]=__uint_as_float(a0.z); ar[3]=__uint_as_float(a0.w);
    ar[4]=__uint_as_float(a1.x); ar[5]=__uint_as_float(a1.y); ar[6]=__uint_as_float(a1.z); ar[7]=__uint_as_float(a1.w);
    ar[8]=__uint_as_float(a2.x); ar[9]=__uint_as_float(a2.y); ar[10]=__uint_as_float(a2.z); ar[11]=__uint_as_float(a2.w);
    ar[12]=__uint_as_float(a3.x); ar[13]=__uint_as_float(a3.y); ar[14]=__uint_as_float(a3.z); ar[15]=__uint_as_float(a3.w);
  }
  for (int n = w; n < N_NODES; n += NF_WAVES){
    int off0 = loc[n]   + bscan[n>>8];
    int off1 = loc[n+1] + bscan[(n+1)>>8];      // loc[50000] valid (padded chunk 195)
    int deg = off1 - off0;
    if (deg == 0){
      ((float2*)(out + (size_t)n*FEATS))[lane] = make_float2(0.f, 0.f);
      continue;
    }
    float kf2[16];
    {
      const unsigned short* kr = kb + (size_t)n*FEATS + h*16;
      uint4 k0 = *(const uint4*)kr;
      uint4 k1 = *(const uint4*)(kr + 8);
      float kf[16]; unpack8(k0, kf); unpack8(k1, kf+8);
      #pragma unroll
      for (int i = 0; i < 16; i++) kf2[i] = -L2E * kf[i];
    }
    float ssum = 0.f;
    float acc[16];
    #pragma unroll
    for (int i = 0; i < 16; i++) acc[i] = 0.f;
    if (g < deg){
      // software pipeline: q-row of edge j+8 prefetched during edge j's compute;
      // v-row of edge j issued at iteration top (use is ~350cy later -> hidden);
      // CSR index kept two edges ahead.
      int sA = src_csr[off0 + g];
      int jB = g + 8;
      int sB = (jB < deg) ? src_csr[off0 + jB] : sA;   // dup tail -> L1 hit
      const unsigned short* pA = qv + (size_t)sA*256 + h*16;
      uint4 qa0 = *(const uint4*)pA;
      uint4 qa1 = *(const uint4*)(pA + 8);
      while (true){
        uint4 va0 = *(const uint4*)(pA + 128);   // current v (interleaved row)
        uint4 va1 = *(const uint4*)(pA + 136);
        const unsigned short* pB = qv + (size_t)sB*256 + h*16;
        uint4 qb0 = *(const uint4*)pB;           // next q prefetch
        uint4 qb1 = *(const uint4*)(pB + 8);
        int jC = jB + 8;
        int sC = (jC < deg) ? src_csr[off0 + jC] : sB;
        float qf[16]; unpack8(qa0, qf); unpack8(qa1, qf+8);
        float t = 0.f;
        #pragma unroll
        for (int i = 0; i < 16; i++){
          float xs = fmaf(qf[i], -L2E, kf2[i]);
          float sg = __builtin_amdgcn_rcpf(1.f + __builtin_amdgcn_exp2f(xs));
          t = fmaf(ar[i], sg, t);
        }
        float ex = __builtin_amdgcn_exp2f(t * L2E);   // |t|<=sum|attn| -> max-free safe
        ssum += ex;
        float vf[16]; unpack8(va0, vf); unpack8(va1, vf+8);
        #pragma unroll
        for (int i = 0; i < 16; i++) acc[i] = fmaf(ex, vf[i], acc[i]);
        if (jB >= deg) break;
        qa0 = qb0; qa1 = qb1; pA = pB;
        jB = jC; sB = sC;
      }
    }
    ssum += __shfl_xor(ssum, 8); ssum += __shfl_xor(ssum, 16); ssum += __shfl_xor(ssum, 32);
    #pragma unroll
    for (int i = 0; i < 16; i++){
      acc[i] += __shfl_xor(acc[i], 8);
      acc[i] += __shfl_xor(acc[i], 16);
      acc[i] += __shfl_xor(acc[i], 32);
    }
    if (g == 0){
      float inv_s = 1.f / ssum;
      float4* op = (float4*)(out + (size_t)n*FEATS + h*16);
      op[0] = make_float4(acc[0]*inv_s, acc[1]*inv_s, acc[2]*inv_s, acc[3]*inv_s);
      op[1] = make_float4(acc[4]*inv_s, acc[5]*inv_s, acc[6]*inv_s, acc[7]*inv_s);
      op[2] = make_float4(acc[8]*inv_s, acc[9]*inv_s, acc[10]*inv_s, acc[11]*inv_s);
      op[3] = make_float4(acc[12]*inv_s, acc[13]*inv_s, acc[14]*inv_s, acc[15]*inv_s);
    }
  }
}

extern "C" void kernel_launch(void* const* d_in, const int* in_sizes, int n_in,
                              void* d_out, int out_size, void* d_ws, size_t ws_size,
                              hipStream_t stream){
  (void)in_sizes; (void)n_in; (void)out_size; (void)ws_size;
  const float* ftq  = (const float*)d_in[0];
  const float* ftk  = (const float*)d_in[1];
  const int*   srcE = (const int*)d_in[2];
  const int*   dstE = (const int*)d_in[3];
  const float* Wq   = (const float*)d_in[4];
  const float* bq   = (const float*)d_in[5];
  const float* Wk   = (const float*)d_in[6];
  const float* Wv   = (const float*)d_in[7];
  const float* attn = (const float*)d_in[8];
  const float* gq   = (const float*)d_in[9];
  const float* bqn  = (const float*)d_in[10];
  const float* gk   = (const float*)d_in[11];
  const float* bkn  = (const float*)d_in[12];

  char* ws = (char*)d_ws;
  int*   counts  = (int*)(ws + 0);               // CPAD ints   [0, 200704)
  float* sums    = (float*)(ws + 200704);        // 512 f       [200704, 202752)
  int*   csums   = (int*)(ws + 202752);          // 196 ints    [202752, 203536) <- memset end
  int*   loc     = (int*)(ws + 203536);          // CPAD ints   [203536, 404240)
  int*   bscan   = (int*)(ws + 404240);          // 196 ints
  int*   src_csr = (int*)(ws + 405024);          // 800000 ints [405024, 3605024)
  unsigned short* rankE = (unsigned short*)(ws + 3605024);  // 800000 u16 [3605024, 5205024)
  unsigned short* Wb = (unsigned short*)(ws + 5205024);     // 3*128*128 bf16
  float* biasf   = (float*)(ws + 5303328);       // 384 f
  unsigned short* qv = (unsigned short*)(ws + 5304864);     // 50000*256 bf16 (q|v interleaved)
  unsigned short* kb = qv + (size_t)N_NODES*256;            // 50000*128 bf16
  float* out = (float*)d_out;

  hipMemsetAsync(ws, 0, 203536, stream);  // counts, sums, csums

  hipLaunchKernelGGL(stats_hist_kernel, dim3(STAT_BLOCKS + HIST_BLOCKS), dim3(256), 0, stream,
                     ftq, ftk, sums, dstE, counts, csums, rankE);
  hipLaunchKernelGGL(scan_fold_kernel, dim3(293), dim3(256), 0, stream,
                     counts, csums, loc, bscan,
                     Wq, bq, Wk, Wv, gq, bqn, gk, bkn, sums, Wb, biasf);
  hipLaunchKernelGGL(gemm_scatter_kernel, dim3(GEMM_BLOCKS + SCAT_BLOCKS), dim3(256), 0, stream,
                     ftq, ftk, Wb, biasf, qv, kb, dstE, srcE, loc, bscan, rankE, src_csr);
  hipLaunchKernelGGL(node_fused_kernel, dim3(NF_WAVES/4), dim3(256), 0, stream,
                     qv, kb, attn, src_csr, loc, bscan, out);
}